// Round 6
// baseline (86.556 us; speedup 1.0000x reference)
//
#include <hip/hip_runtime.h>
#include <math.h>

#define CCH 256
#define NN  4096
#define NHEAD 8
#define CONDD 512

typedef __attribute__((ext_vector_type(8))) short short8;
typedef __attribute__((ext_vector_type(4))) float f32x4;
typedef __attribute__((ext_vector_type(16))) float f32x16;

static __device__ __forceinline__ short f2bf(float f) {
    union { float f; uint32_t u; } v; v.f = f;
    uint32_t r = v.u + 0x7fffu + ((v.u >> 16) & 1u);   // RNE
    return (short)(r >> 16);
}

static __device__ __forceinline__ uint32_t cvt_pk_bf16(float a, float b) {
    uint32_t r;
    asm("v_cvt_pk_bf16_f32 %0, %1, %2" : "=v"(r) : "v"(a), "v"(b));
    return r;
}

// ---------------- fused front: group stats | weight conv | adagn linear ----------------
__global__ __launch_bounds__(256) void front_fused(const float* __restrict__ x,
                                                   const float* __restrict__ cond,
                                                   const float* __restrict__ w_scale,
                                                   const float* __restrict__ b_scale,
                                                   const float* __restrict__ w_shift,
                                                   const float* __restrict__ b_shift,
                                                   const float* __restrict__ wq,
                                                   const float* __restrict__ wo,
                                                   float* __restrict__ partial,
                                                   float* __restrict__ scale,
                                                   float* __restrict__ shift,
                                                   short* __restrict__ wqb,
                                                   short* __restrict__ wob) {
    __shared__ float rs[4], rss[4];
    int bb = blockIdx.x;
    int t = threadIdx.x;
    if (bb < 256) {
        const float4* p = (const float4*)(x + bb * 4096);
        float s = 0.f, ss = 0.f;
        for (int k = t; k < 1024; k += 256) {
            float4 v = p[k];
            s += v.x + v.y + v.z + v.w;
            ss += v.x * v.x + v.y * v.y + v.z * v.z + v.w * v.w;
        }
        #pragma unroll
        for (int off = 32; off; off >>= 1) { s += __shfl_xor(s, off); ss += __shfl_xor(ss, off); }
        int wid = t >> 6;
        if ((t & 63) == 0) { rs[wid] = s; rss[wid] = ss; }
        __syncthreads();
        if (t == 0) {
            partial[2 * bb] = rs[0] + rs[1] + rs[2] + rs[3];
            partial[2 * bb + 1] = rss[0] + rss[1] + rss[2] + rss[3];
        }
    } else if (bb < 1280) {
        int idx = (bb - 256) * 256 + t;
        if (idx < 196608) wqb[idx] = f2bf(wq[idx]);
        else              wob[idx - 196608] = f2bf(wo[idx - 196608]);
    } else {
        int o = (bb - 1280) * 4 + (t >> 6);
        int lane = t & 63;
        float ds = 0.f, dh = 0.f;
        for (int k = lane; k < CONDD; k += 64) {
            float cv = cond[k];
            ds += cv * w_scale[o * CONDD + k];
            dh += cv * w_shift[o * CONDD + k];
        }
        #pragma unroll
        for (int off = 32; off; off >>= 1) { ds += __shfl_xor(ds, off); dh += __shfl_xor(dh, off); }
        if (lane == 0) { scale[o] = ds + b_scale[o]; shift[o] = dh + b_shift[o]; }
    }
}

// ---------------- normalize + affine -> bf16 transposed norm_t[i][c] ----------------
__global__ __launch_bounds__(256) void normalize_t(const float* __restrict__ x,
                                                   const float* __restrict__ partial,
                                                   const float* __restrict__ scale,
                                                   const float* __restrict__ shift,
                                                   short* __restrict__ norm_t) {
    __shared__ float gm[8], gr[8];
    __shared__ float Aa[64], Bb[64];
    __shared__ short tile[32 * 66];
    int i0 = blockIdx.x * 32;
    int c0 = blockIdx.y * 64;
    int g0 = c0 >> 3;
    int t = threadIdx.x;
    if (t < 8) {
        float s = 0.f, ss = 0.f;
        #pragma unroll
        for (int ch = 0; ch < 8; ++ch) {
            s += partial[((g0 + t) * 8 + ch) * 2];
            ss += partial[((g0 + t) * 8 + ch) * 2 + 1];
        }
        float mean = s * (1.0f / 32768.0f);
        float var = ss * (1.0f / 32768.0f) - mean * mean;
        gm[t] = mean;
        gr[t] = rsqrtf(var + 1e-6f);
    }
    __syncthreads();
    if (t < 64) {
        int c = c0 + t;
        float a = gr[t >> 3] * (1.0f + scale[c]);
        Aa[t] = a;
        Bb[t] = shift[c] - gm[t >> 3] * a;
    }
    __syncthreads();
    #pragma unroll
    for (int e0 = 0; e0 < 8; ++e0) {
        int e = e0 * 256 + t;
        int cl = e >> 5, il = e & 31;
        float v = x[(c0 + cl) * NN + i0 + il];
        tile[il * 66 + cl] = f2bf(v * Aa[cl] + Bb[cl]);
    }
    __syncthreads();
    #pragma unroll
    for (int e0 = 0; e0 < 4; ++e0) {
        int e = e0 * 256 + t;
        int il = e >> 5, cd = e & 31;
        uint32_t d = *(const uint32_t*)&tile[il * 66 + 2 * cd];
        *(uint32_t*)&norm_t[(i0 + il) * 256 + c0 + 2 * cd] = d;
    }
}

// ---------------- QKV GEMM: wave = 32o x 16i, grid (24, 64) ----------------
// Q pre-scaled by log2(e)/16 so attention can use exp2 directly.
__global__ __launch_bounds__(256) void qkv_gemm(const short* __restrict__ wqb,
                                                const short* __restrict__ norm_t,
                                                short* __restrict__ qtb, short* __restrict__ ktb,
                                                short* __restrict__ vcb) {
    int t = threadIdx.x;
    int w = t >> 6, lane = t & 63, li = lane & 15, lg = lane >> 4;
    int o0 = blockIdx.x * 32;
    int i0 = blockIdx.y * 64 + w * 16;
    f32x4 acc[2] = {{0,0,0,0},{0,0,0,0}};
    const short* bbase = norm_t + (i0 + li) * 256 + 8 * lg;
    const short* abase = wqb + (o0 + li) * 256 + 8 * lg;
    #pragma unroll
    for (int ks = 0; ks < 8; ++ks) {
        short8 bfrag = *(const short8*)(bbase + ks * 32);
        #pragma unroll
        for (int f = 0; f < 2; ++f) {
            short8 afrag = *(const short8*)(abase + f * 16 * 256 + ks * 32);
            acc[f] = __builtin_amdgcn_mfma_f32_16x16x32_bf16(afrag, bfrag, acc[f], 0, 0, 0);
        }
    }
    int i = i0 + li;
    #pragma unroll
    for (int f = 0; f < 2; ++f) {
        #pragma unroll
        for (int r = 0; r < 4; ++r) {
            int o = o0 + 16 * f + 4 * lg + r;
            float v = acc[f][r];
            int h = o / 96;
            int rr = o - h * 96;
            int cc = rr & 31;
            int kind = rr >> 5;
            if (kind == 0)      qtb[(h * NN + i) * 32 + cc] = f2bf(v * (0.0625f * 1.44269504f));
            else if (kind == 1) ktb[(h * NN + i) * 32 + cc] = f2bf(v);
            else                vcb[(h * 32 + cc) * NN + i] = f2bf(v);
        }
    }
}

// ---------------- flash attention helpers ----------------
union PF { uint32_t u[4]; short8 s8; };

static __device__ __forceinline__ f32x16 qk_tile(short8 k0, short8 k1, short8 qf0, short8 qf1) {
    const f32x16 z = {0,0,0,0,0,0,0,0,0,0,0,0,0,0,0,0};
    __builtin_amdgcn_s_setprio(1);
    f32x16 s = __builtin_amdgcn_mfma_f32_32x32x16_bf16(k0, qf0, z, 0, 0, 0);
    s = __builtin_amdgcn_mfma_f32_32x32x16_bf16(k1, qf1, s, 0, 0, 0);
    __builtin_amdgcn_s_setprio(0);
    return s;
}

static __device__ __forceinline__ void pv_tile(f32x16 s, short8 v0, short8 v1,
                                               f32x16& acc, float& lsum) {
    float p[16];
    #pragma unroll
    for (int r = 0; r < 16; ++r) p[r] = __builtin_amdgcn_exp2f(s[r]);
    float u0 = 0.f, u1 = 0.f;
    #pragma unroll
    for (int r = 0; r < 4; ++r) { u0 += p[r] + p[4 + r]; u1 += p[8 + r] + p[12 + r]; }
    lsum += u0 + u1;
    auto A1 = __builtin_amdgcn_permlane32_swap(cvt_pk_bf16(p[0], p[1]),   cvt_pk_bf16(p[4], p[5]),   false, false);
    auto A2 = __builtin_amdgcn_permlane32_swap(cvt_pk_bf16(p[2], p[3]),   cvt_pk_bf16(p[6], p[7]),   false, false);
    auto A3 = __builtin_amdgcn_permlane32_swap(cvt_pk_bf16(p[8], p[9]),   cvt_pk_bf16(p[12], p[13]), false, false);
    auto A4 = __builtin_amdgcn_permlane32_swap(cvt_pk_bf16(p[10], p[11]), cvt_pk_bf16(p[14], p[15]), false, false);
    PF f1, f2;
    f1.u[0] = A1[0]; f1.u[1] = A2[0]; f1.u[2] = A1[1]; f1.u[3] = A2[1];   // local j 0..15
    f2.u[0] = A3[0]; f2.u[1] = A4[0]; f2.u[2] = A3[1]; f2.u[3] = A4[1];   // local j 16..31
    __builtin_amdgcn_s_setprio(1);
    acc = __builtin_amdgcn_mfma_f32_32x32x16_bf16(v0, f1.s8, acc, 0, 0, 0);
    acc = __builtin_amdgcn_mfma_f32_32x32x16_bf16(v1, f2.s8, acc, 0, 0, 0);
    __builtin_amdgcn_s_setprio(0);
}

// ---------------- flash attention: 32x32 MFMA, permlane, XCD-pinned, 2-stage pipeline ----
// grid 1024: head = bid & 7 (pins each head's K/V to one XCD's L2), qb = bid >> 3.
// 4 waves split keys 4-way (1024 each); 32-key tiles, S(t+1) computed while S(t) consumed.
__global__ __launch_bounds__(256, 4) void attention_mfma(const short* __restrict__ qtb,
                                                         const short* __restrict__ ktb,
                                                         const short* __restrict__ vcb,
                                                         short* __restrict__ attnT) {
    __shared__ float lds_acc[4][32][32];
    __shared__ float lds_lsum[4][32];

    int bid = blockIdx.x;
    int h = bid & 7;
    int i_base = (bid >> 3) * 32;
    int t = threadIdx.x;
    int w = t >> 6, lane = t & 63, l31 = lane & 31, hi = lane >> 5;

    const short* qrow = qtb + (h * NN + i_base + l31) * 32;
    short8 qf0 = *(const short8*)(qrow + 8 * hi);        // c 0..15 half
    short8 qf1 = *(const short8*)(qrow + 16 + 8 * hi);   // c 16..31 half

    const short* kbase = ktb + (h * NN + l31) * 32 + 8 * hi;   // + j*32
    const short* vrow  = vcb + (h * 32 + l31) * NN + 8 * hi;   // + j

    f32x16 acc = {0,0,0,0,0,0,0,0,0,0,0,0,0,0,0,0};
    float lsum = 0.f;

    int jstart = w * 1024;
    const short* kp = kbase + jstart * 32;
    const short* vp = vrow + jstart;

    // prologue: K(0), V(0), S(0); then K(1)
    short8 k0 = *(const short8*)kp, k1 = *(const short8*)(kp + 16);
    short8 v0 = *(const short8*)vp, v1 = *(const short8*)(vp + 16);
    f32x16 sA = qk_tile(k0, k1, qf0, qf1);
    kp += 1024; k0 = *(const short8*)kp; k1 = *(const short8*)(kp + 16);
    f32x16 sB;

    // invariant at pair p: k = K(2p+1), sA = S(2p), v = V(2p)
    #pragma unroll 1
    for (int p = 0; p < 15; ++p) {
        sB = qk_tile(k0, k1, qf0, qf1);                                   // S(2p+1)
        kp += 1024; k0 = *(const short8*)kp; k1 = *(const short8*)(kp + 16);  // K(2p+2)
        pv_tile(sA, v0, v1, acc, lsum);                                   // tile 2p
        vp += 32; v0 = *(const short8*)vp; v1 = *(const short8*)(vp + 16);    // V(2p+1)

        sA = qk_tile(k0, k1, qf0, qf1);                                   // S(2p+2)
        kp += 1024; k0 = *(const short8*)kp; k1 = *(const short8*)(kp + 16);  // K(2p+3)
        pv_tile(sB, v0, v1, acc, lsum);                                   // tile 2p+1
        vp += 32; v0 = *(const short8*)vp; v1 = *(const short8*)(vp + 16);    // V(2p+2)
    }
    // epilogue: k = K(31), sA = S(30), v = V(30)
    sB = qk_tile(k0, k1, qf0, qf1);                                       // S(31)
    pv_tile(sA, v0, v1, acc, lsum);                                       // tile 30
    vp += 32; v0 = *(const short8*)vp; v1 = *(const short8*)(vp + 16);        // V(31)
    pv_tile(sB, v0, v1, acc, lsum);                                       // tile 31

    lsum += __shfl_xor(lsum, 32);

    #pragma unroll
    for (int r = 0; r < 16; ++r) {
        int c = (r & 3) + 8 * (r >> 2) + 4 * hi;
        lds_acc[w][c][l31] = acc[r];
    }
    if (hi == 0) lds_lsum[w][l31] = lsum;
    __syncthreads();

    int q = t & 31, c0 = (t >> 5) * 4;
    float s0 = 0.f, s1 = 0.f, s2 = 0.f, s3 = 0.f, ls = 0.f;
    #pragma unroll
    for (int ww = 0; ww < 4; ++ww) {
        s0 += lds_acc[ww][c0 + 0][q];
        s1 += lds_acc[ww][c0 + 1][q];
        s2 += lds_acc[ww][c0 + 2][q];
        s3 += lds_acc[ww][c0 + 3][q];
        ls += lds_lsum[ww][q];
    }
    float inv = 1.0f / ls;
    uint2 uu;
    uu.x = cvt_pk_bf16(s0 * inv, s1 * inv);
    uu.y = cvt_pk_bf16(s2 * inv, s3 * inv);
    *(uint2*)&attnT[(i_base + q) * 256 + h * 32 + c0] = uu;
}

// ---------------- out projection GEMM + bias + residual: wave = 32o x 16i ----------------
__global__ __launch_bounds__(256) void proj_gemm(const short* __restrict__ wob,
                                                 const short* __restrict__ attnT,
                                                 const float* __restrict__ b_out,
                                                 const float* __restrict__ x,
                                                 float* __restrict__ out) {
    int t = threadIdx.x;
    int w = t >> 6, lane = t & 63, li = lane & 15, lg = lane >> 4;
    int o0 = blockIdx.x * 32;
    int i0 = blockIdx.y * 64 + w * 16;
    f32x4 acc[2] = {{0,0,0,0},{0,0,0,0}};
    const short* bbase = attnT + (i0 + li) * 256 + 8 * lg;
    const short* abase = wob + (o0 + li) * 256 + 8 * lg;
    #pragma unroll
    for (int ks = 0; ks < 8; ++ks) {
        short8 bfrag = *(const short8*)(bbase + ks * 32);
        #pragma unroll
        for (int f = 0; f < 2; ++f) {
            short8 afrag = *(const short8*)(abase + f * 16 * 256 + ks * 32);
            acc[f] = __builtin_amdgcn_mfma_f32_16x16x32_bf16(afrag, bfrag, acc[f], 0, 0, 0);
        }
    }
    int i = i0 + li;
    #pragma unroll
    for (int f = 0; f < 2; ++f) {
        #pragma unroll
        for (int r = 0; r < 4; ++r) {
            int o = o0 + 16 * f + 4 * lg + r;
            out[o * NN + i] = acc[f][r] + b_out[o] + x[o * NN + i];
        }
    }
}

extern "C" void kernel_launch(void* const* d_in, const int* in_sizes, int n_in,
                              void* d_out, int out_size, void* d_ws, size_t ws_size,
                              hipStream_t stream) {
    const float* x       = (const float*)d_in[0];
    const float* cond    = (const float*)d_in[1];
    const float* w_scale = (const float*)d_in[2];
    const float* b_scale = (const float*)d_in[3];
    const float* w_shift = (const float*)d_in[4];
    const float* b_shift = (const float*)d_in[5];
    const float* w_qkv   = (const float*)d_in[6];
    const float* w_out   = (const float*)d_in[7];
    const float* b_out   = (const float*)d_in[8];
    float* out = (float*)d_out;

    float* ws = (float*)d_ws;
    float* scale   = ws;            // 256
    float* shift   = ws + 256;      // 256
    float* partial = ws + 512;      // 512
    short* norm_t = (short*)(ws + 1024);     // [i][c] 1M bf16
    short* qtb = norm_t + 1048576;           // [h][i][c] (scaled by log2e/16)
    short* ktb = qtb + 1048576;              // [h][j][c]
    short* vcb = ktb + 1048576;              // [h][c][j]
    short* attnT = vcb + 1048576;            // [i][c] 1M bf16
    short* wqb = attnT + 1048576;            // 768*256
    short* wob = wqb + 768 * 256;            // 256*256

    front_fused<<<1344, 256, 0, stream>>>(x, cond, w_scale, b_scale, w_shift, b_shift,
                                          w_qkv, w_out, partial, scale, shift, wqb, wob);
    normalize_t<<<dim3(128, 4), 256, 0, stream>>>(x, partial, scale, shift, norm_t);
    qkv_gemm<<<dim3(24, 64), 256, 0, stream>>>(wqb, norm_t, qtb, ktb, vcb);
    attention_mfma<<<1024, 256, 0, stream>>>(qtb, ktb, vcb, attnT);
    proj_gemm<<<dim3(8, 64), 256, 0, stream>>>(wob, attnT, b_out, x, out);
}